// Round 13
// baseline (1358.718 us; speedup 1.0000x reference)
//
#include <hip/hip_runtime.h>

// GNNModel fused via MFMA. R13 = R12 body (lean: 40 VGPR, spill-free,
// tT-free via K=16 C->A chaining) wrapped in a persistent grid-stride loop
// (grid 4096 x 4 groups). R12 counters: static occupancy cap 100% but
// measured 67.5% with block-cycle capacity ~= consumption -> wave slots
// idle during block launch/drain churn (16384 short blocks). Persistence
// amortizes fixed costs and lets resident waves backfill. NOTHING is held
// in registers across iterations (R5/R6's spill trap).

typedef _Float16 half4v __attribute__((ext_vector_type(4)));
typedef _Float16 half8v __attribute__((ext_vector_type(8)));
typedef float    float4v __attribute__((ext_vector_type(4)));

constexpr int PP = 12, DIN = 32, H = 128, HO = 64, DOUT = 3, NL = 3;
constexpr int NB = 4, ROWS = NB * PP;   // 48 rows per group
constexpr int HP  = 136;                // h_a stride (halves)
constexpr int AP2 = 72;                 // AmatT stride (halves)
constexpr int GRID = 4096;              // persistent blocks; ngroups = B/(GRID*NB)

// ws layout in halves: WinT[128][32] @0 ; WgT[3][128][128] @4096 ; W1T[64][128] @53248
constexpr int WS_WG = 4096, WS_W1 = 53248, WS_TOT = 61440;

__global__ __launch_bounds__(256)
void prep_weights(const float* __restrict__ W_in, const float* __restrict__ W_gcn,
                  const float* __restrict__ W_out1, _Float16* __restrict__ ws)
{
    int e = blockIdx.x * 256 + threadIdx.x;
    if (e < WS_WG) {                        // WinT[n][k] = W_in[k][n]
        int n = e >> 5, k = e & 31;
        ws[e] = (_Float16)W_in[k * H + n];
    } else if (e < WS_W1) {                 // WgT[l][n][k] = W_gcn[l][k][n]
        int e2 = e - WS_WG;
        int l = e2 >> 14, r = e2 & 16383, n = r >> 7, k = r & 127;
        ws[e] = (_Float16)W_gcn[l * (H * H) + k * H + n];
    } else if (e < WS_TOT) {                // W1T[o][k] = W_out1[k][o]
        int e3 = e - WS_W1;
        int o = e3 >> 7, k = e3 & 127;
        ws[e] = (_Float16)W_out1[k * HO + o];
    }
}

__device__ inline half4v pk4(float a, float b, float c, float d) {
    half4v r; r[0] = (_Float16)a; r[1] = (_Float16)b; r[2] = (_Float16)c; r[3] = (_Float16)d;
    return r;
}

__global__ __launch_bounds__(256, 4)
void gnn_mfma(const float* __restrict__ x,
              const float* __restrict__ b_in,
              const float* __restrict__ b_gcn,
              const float* __restrict__ b_out1,
              const float* __restrict__ W_out2,
              const float* __restrict__ b_out2,
              const _Float16* __restrict__ ws,
              float* __restrict__ out,
              int ngroups)
{
    __shared__ _Float16 h_a[ROWS][HP];                 // 12.75 KB
    __shared__ __align__(16) char r3[ROWS * AP2 * 2];  // 6.75 KB: AmatT, aliased g_s
    _Float16 (*AmatT)[AP2] = (_Float16 (*)[AP2])r3;
    float (*g_s)[H] = (float (*)[H])r3;                // [4][128] fp32 (2 KB)

    const int tid  = threadIdx.x;
    const int lane = tid & 63, wave = tid >> 6;
    const int q = lane >> 4, qm = lane & 15;
    const _Float16* WgT = ws + WS_WG;

    #pragma unroll 1
    for (int g = 0; g < ngroups; ++g) {
        const int b0 = (g * GRID + blockIdx.x) * NB;
        const float* xblk = x + (size_t)b0 * (PP * DIN);

        // B0: previous group's tail reads of h_a (pool, cross-wave cols) and
        // g_s (aliases AmatT) are done before this group's proj/adjacency writes.
        __syncthreads();

        // ---- x loads (lon + proj B-frag quads) ----
        float lon_own = 0.f;
        if (lane < PP) lon_own = xblk[(wave * PP + lane) * DIN];
        float4 xa[3], xb[3];
        #pragma unroll
        for (int nt = 0; nt < 3; ++nt) {
            const float* p = xblk + (16 * nt + qm) * DIN + 8 * q;
            xa[nt] = *(const float4*)p;
            xb[nt] = *(const float4*)(p + 4);
        }

        // ---- adjacency via shfl (bit-exact fp32 mask); wave w = batch w ----
        {
            float lonj[PP];
            #pragma unroll
            for (int j = 0; j < PP; ++j) lonj[j] = __shfl(lon_own, j, 64);
            float deg = 1.0f;                          // GCNConv's appended self-loop
            #pragma unroll
            for (int j = 0; j < PP; ++j) {
                float d = fabsf(lon_own - lonj[j]);
                d = fminf(d, 360.0f - d);
                deg += (d < 10.0f) ? 1.0f : 0.0f;      // diag: d=0 -> 1
            }
            float dinv_own = rsqrtf(fmaxf(deg, 1e-12f));
            float dj[PP];
            #pragma unroll
            for (int j = 0; j < PP; ++j) dj[j] = __shfl(dinv_own, j, 64);

            if (lane < PP) {
                const int n = wave * PP + lane;
                half8v z = {0, 0, 0, 0, 0, 0, 0, 0};
                #pragma unroll
                for (int c = 0; c < 48; c += 8) *(half8v*)&AmatT[n][c] = z;
                _Float16 vals[PP];
                #pragma unroll
                for (int j = 0; j < PP; ++j) {
                    float d = fabsf(lon_own - lonj[j]);
                    d = fminf(d, 360.0f - d);
                    float a = (d < 10.0f) ? 1.0f : 0.0f;
                    if (j == lane) a += 1.0f;          // A = mask + eye: diag = 2
                    vals[j] = (_Float16)(a * dinv_own * dj[j]);
                }
                #pragma unroll
                for (int t4 = 0; t4 < 3; ++t4) {
                    half4v v;
                    v[0] = vals[4 * t4]; v[1] = vals[4 * t4 + 1];
                    v[2] = vals[4 * t4 + 2]; v[3] = vals[4 * t4 + 3];
                    *(half4v*)&AmatT[n][wave * PP + 4 * t4] = v;
                }
            }
        }

        // ---- proj: h0^T = WinT @ x^T -> h_a[planet row][wave-own cols] ----
        {
            half8v bx[3];
            #pragma unroll
            for (int nt = 0; nt < 3; ++nt) {
                half8v h;
                h[0] = (_Float16)xa[nt].x; h[1] = (_Float16)xa[nt].y;
                h[2] = (_Float16)xa[nt].z; h[3] = (_Float16)xa[nt].w;
                h[4] = (_Float16)xb[nt].x; h[5] = (_Float16)xb[nt].y;
                h[6] = (_Float16)xb[nt].z; h[7] = (_Float16)xb[nt].w;
                bx[nt] = h;
            }
            #pragma unroll
            for (int mt2 = 0; mt2 < 2; ++mt2) {
                const int m = 32 * wave + 16 * mt2;
                half8v aw = *(const half8v*)&ws[(m + qm) * DIN + 8 * q];
                float4 bi = *(const float4*)&b_in[m + 4 * q];
                #pragma unroll
                for (int nt = 0; nt < 3; ++nt) {
                    float4v c = {0.f, 0.f, 0.f, 0.f};
                    c = __builtin_amdgcn_mfma_f32_16x16x32_f16(aw, bx[nt], c, 0, 0, 0);
                    *(half4v*)&h_a[16 * nt + qm][m + 4 * q] =
                        pk4(c[0] + bi.x, c[1] + bi.y, c[2] + bi.z, c[3] + bi.w);
                }
            }
        }
        __syncthreads();   // B1: h_a + AmatT complete

        // ---- GCN layers ----
        #pragma unroll
        for (int l = 0; l < NL; ++l) {
            const _Float16* Wl = WgT + l * (H * H);
            half8v bw[2][4];
            #pragma unroll
            for (int n2 = 0; n2 < 2; ++n2)
                #pragma unroll
                for (int kt = 0; kt < 4; ++kt)
                    bw[n2][kt] = *(const half8v*)&Wl[(32 * wave + 16 * n2 + qm) * H + 32 * kt + 8 * q];

            // t = h @ Wl
            float4v c[3][2];
            #pragma unroll
            for (int mt = 0; mt < 3; ++mt) {
                c[mt][0] = (float4v){0.f, 0.f, 0.f, 0.f};
                c[mt][1] = (float4v){0.f, 0.f, 0.f, 0.f};
            }
            #pragma unroll
            for (int kt = 0; kt < 4; ++kt)
                #pragma unroll
                for (int mt = 0; mt < 3; ++mt) {
                    half8v a = *(const half8v*)&h_a[16 * mt + qm][32 * kt + 8 * q];
                    c[mt][0] = __builtin_amdgcn_mfma_f32_16x16x32_f16(a, bw[0][kt], c[mt][0], 0, 0, 0);
                    c[mt][1] = __builtin_amdgcn_mfma_f32_16x16x32_f16(a, bw[1][kt], c[mt][1], 0, 0, 0);
                }

            // pack t C-tiles -> mix A-frags (t^T), in-register (chaining identity)
            half4v ah[3][2];
            #pragma unroll
            for (int mt = 0; mt < 3; ++mt)
                #pragma unroll
                for (int n2 = 0; n2 < 2; ++n2)
                    ah[mt][n2] = pk4(c[mt][n2][0], c[mt][n2][1], c[mt][n2][2], c[mt][n2][3]);

            __syncthreads();   // B2: WAR on h_a

            // mix: h'^T = t^T @ Amat; Amat B-frags from LDS (b64)
            half4v bA[3][3];   // [kt][nt]
            #pragma unroll
            for (int kt = 0; kt < 3; ++kt)
                #pragma unroll
                for (int nt = 0; nt < 3; ++nt)
                    bA[kt][nt] = *(const half4v*)&AmatT[16 * nt + qm][16 * kt + 4 * q];

            #pragma unroll
            for (int n2 = 0; n2 < 2; ++n2) {
                float4 bg = *(const float4*)&b_gcn[l * H + 32 * wave + 16 * n2 + 4 * q];
                #pragma unroll
                for (int nt = 0; nt < 3; ++nt) {
                    float4v d = {0.f, 0.f, 0.f, 0.f};
                    d = __builtin_amdgcn_mfma_f32_16x16x16f16(ah[0][n2], bA[0][nt], d, 0, 0, 0);
                    d = __builtin_amdgcn_mfma_f32_16x16x16f16(ah[1][n2], bA[1][nt], d, 0, 0, 0);
                    d = __builtin_amdgcn_mfma_f32_16x16x16f16(ah[2][n2], bA[2][nt], d, 0, 0, 0);
                    *(half4v*)&h_a[16 * nt + qm][32 * wave + 16 * n2 + 4 * q] =
                        pk4(fmaxf(d[0] + bg.x, 0.f), fmaxf(d[1] + bg.y, 0.f),
                            fmaxf(d[2] + bg.z, 0.f), fmaxf(d[3] + bg.w, 0.f));
                }
            }
            __syncthreads();   // B3: RAW for next layer / pool
        }

        // ---- tail: wave w owns batch w ----
        {
            float s0 = 0.f, s1 = 0.f;
            #pragma unroll
            for (int p = 0; p < PP; ++p) {
                s0 += (float)h_a[wave * PP + p][lane];
                s1 += (float)h_a[wave * PP + p][lane + 64];
            }
            g_s[wave][lane]      = s0 * (1.0f / 12.0f);   // r3 alias: AmatT dead
            g_s[wave][lane + 64] = s1 * (1.0f / 12.0f);
        }
        float o1;
        {
            float acc = b_out1[lane];
            const _Float16* wr = ws + WS_W1 + lane * H;
            #pragma unroll
            for (int kk = 0; kk < H / 8; ++kk) {
                half8v wv = *(const half8v*)&wr[8 * kk];
                #pragma unroll
                for (int j = 0; j < 8; ++j) acc += g_s[wave][8 * kk + j] * (float)wv[j];
            }
            o1 = fmaxf(acc, 0.f);
        }
        {
            float p0 = o1 * W_out2[lane * DOUT + 0];
            float p1 = o1 * W_out2[lane * DOUT + 1];
            float p2 = o1 * W_out2[lane * DOUT + 2];
            #pragma unroll
            for (int off = 32; off > 0; off >>= 1) {
                p0 += __shfl_down(p0, off, 64);
                p1 += __shfl_down(p1, off, 64);
                p2 += __shfl_down(p2, off, 64);
            }
            if (lane == 0) {
                float* o = out + (size_t)(b0 + wave) * DOUT;
                o[0] = p0 + b_out2[0];
                o[1] = p1 + b_out2[1];
                o[2] = p2 + b_out2[2];
            }
        }
    }
}

extern "C" void kernel_launch(void* const* d_in, const int* in_sizes, int n_in,
                              void* d_out, int out_size, void* d_ws, size_t ws_size,
                              hipStream_t stream) {
    const float* x      = (const float*)d_in[0];
    const float* W_in   = (const float*)d_in[1];
    const float* b_in   = (const float*)d_in[2];
    const float* W_gcn  = (const float*)d_in[3];
    const float* b_gcn  = (const float*)d_in[4];
    const float* W_out1 = (const float*)d_in[5];
    const float* b_out1 = (const float*)d_in[6];
    const float* W_out2 = (const float*)d_in[7];
    const float* b_out2 = (const float*)d_in[8];
    float* outp         = (float*)d_out;
    _Float16* wsh       = (_Float16*)d_ws;

    const int B = in_sizes[0] / (PP * DIN);        // 65536
    const int ngroups = B / (GRID * NB);           // 4

    hipLaunchKernelGGL(prep_weights, dim3((WS_TOT + 255) / 256), dim3(256), 0, stream,
                       W_in, W_gcn, W_out1, wsh);
    hipLaunchKernelGGL(gnn_mfma, dim3(GRID), dim3(256), 0, stream,
                       x, b_in, b_gcn, b_out1, W_out2, b_out2, wsh, outp, ngroups);
}